// Round 4
// baseline (143.896 us; speedup 1.0000x reference)
//
#include <hip/hip_runtime.h>
#include <hip/hip_bf16.h>

typedef __attribute__((ext_vector_type(8))) short bf16x8;
typedef __attribute__((ext_vector_type(8))) unsigned short ushort8;
typedef __attribute__((ext_vector_type(4))) float f32x4;

typedef const __attribute__((address_space(1))) void gvoid;
typedef __attribute__((address_space(3))) void svoid;

__device__ __forceinline__ unsigned short f2bf(float f) {
  union { float f; unsigned int u; } v; v.f = f;
  unsigned int u = v.u;
  unsigned int r = (u + 0x7fffu + ((u >> 16) & 1u)) >> 16;
  return (unsigned short)r;
}

// ---------------- fp32 -> bf16 cast (vectorized) ----------------
__global__ void cast_kernel(const float* __restrict__ in, unsigned short* __restrict__ out, int n4) {
  int i = blockIdx.x * 256 + threadIdx.x;
  if (i < n4) {
    const float4 v = reinterpret_cast<const float4*>(in)[i];
    ushort4 o;
    o.x = f2bf(v.x); o.y = f2bf(v.y); o.z = f2bf(v.z); o.w = f2bf(v.w);
    reinterpret_cast<ushort4*>(out)[i] = o;
  }
}

// ---------------- C[M][N] = A[M][K] * B[N][K]^T, bf16 in, fp32 acc ----------------
template<bool OUT_BF16>
__global__ __launch_bounds__(256) void gemm_bt(const unsigned short* __restrict__ A,
                                               const unsigned short* __restrict__ B,
                                               void* __restrict__ Cv,
                                               int M, int N, int K) {
  constexpr int BM = 128, BK = 32;
  __shared__ alignas(16) unsigned short As[BM * BK];
  __shared__ alignas(16) unsigned short Bs[BM * BK];
  const int tid = threadIdx.x;
  const int l  = tid & 63;
  const int w  = tid >> 6;
  const int wr = w >> 1, wc = w & 1;
  const int lr = l & 15, lg = l >> 4;
  const long tile_m = (long)blockIdx.x * BM;
  const long tile_n = (long)blockIdx.y * BM;

  const int c0 = tid, c1 = tid + 256;
  const unsigned short* pa0 = A + (tile_m + (c0 >> 2)) * (long)K + (c0 & 3) * 8;
  const unsigned short* pa1 = A + (tile_m + (c1 >> 2)) * (long)K + (c1 & 3) * 8;
  const unsigned short* pb0 = B + (tile_n + (c0 >> 2)) * (long)K + (c0 & 3) * 8;
  const unsigned short* pb1 = B + (tile_n + (c1 >> 2)) * (long)K + (c1 & 3) * 8;
  unsigned short* lA0 = As + (w * 64) * 8;
  unsigned short* lA1 = As + (256 + w * 64) * 8;
  unsigned short* lB0 = Bs + (w * 64) * 8;
  unsigned short* lB1 = Bs + (256 + w * 64) * 8;

  f32x4 acc[4][4] = {};

  for (int k0 = 0; k0 < K; k0 += BK) {
    __syncthreads();
    __builtin_amdgcn_global_load_lds((gvoid*)(pa0 + k0), (svoid*)lA0, 16, 0, 0);
    __builtin_amdgcn_global_load_lds((gvoid*)(pa1 + k0), (svoid*)lA1, 16, 0, 0);
    __builtin_amdgcn_global_load_lds((gvoid*)(pb0 + k0), (svoid*)lB0, 16, 0, 0);
    __builtin_amdgcn_global_load_lds((gvoid*)(pb1 + k0), (svoid*)lB1, 16, 0, 0);
    __syncthreads();
    bf16x8 af[4], bfr[4];
#pragma unroll
    for (int m = 0; m < 4; ++m)
      af[m] = *reinterpret_cast<const bf16x8*>(As + (wr * 64 + m * 16 + lr) * BK + lg * 8);
#pragma unroll
    for (int n = 0; n < 4; ++n)
      bfr[n] = *reinterpret_cast<const bf16x8*>(Bs + (wc * 64 + n * 16 + lr) * BK + lg * 8);
#pragma unroll
    for (int m = 0; m < 4; ++m)
#pragma unroll
      for (int n = 0; n < 4; ++n)
        acc[m][n] = __builtin_amdgcn_mfma_f32_16x16x32_bf16(af[m], bfr[n], acc[m][n], 0, 0, 0);
  }

#pragma unroll
  for (int m = 0; m < 4; ++m)
#pragma unroll
    for (int n = 0; n < 4; ++n)
#pragma unroll
      for (int r = 0; r < 4; ++r) {
        long row = tile_m + wr * 64 + m * 16 + lg * 4 + r;
        long col = tile_n + wc * 64 + n * 16 + lr;
        if (OUT_BF16)
          reinterpret_cast<unsigned short*>(Cv)[row * N + col] = f2bf(acc[m][n][r]);
        else
          reinterpret_cast<float*>(Cv)[row * N + col] = acc[m][n][r];
      }
}

// ---------------- causal flash attention (double-buffered, 1 barrier/tile) ----
// grid = 512 blocks, 8 waves x 16 q-rows. Block i: half=i>>8, bx=i&15,
// bh=(i>>4)&15 | half<<4, qtb = half?15-bx:bx (complementary pairing).
// K: global_load_lds w=16 with pre-swizzled SOURCE (slot js fetches col js^(kr&7)),
//    so linear DMA lands swizzled; read side XORs back. Double-buffered.
// V: reg-staged (transpose), loads issued one full tile early; transpose-write to
//    back buffer overlapped with compute. Vt swizzle: slot ^= (d^(d>>3))&7.
// P: per-wave LDS, slot ^= row&7.
__global__ __launch_bounds__(512, 4) void attn_kernel(const unsigned short* __restrict__ qkv,
                                                      unsigned short* __restrict__ o) {
  constexpr int E = 3072, T = 2048;
  __shared__ alignas(16) unsigned short Ks[2][64 * 64];
  __shared__ alignas(16) unsigned short Vt[2][64 * 64];
  __shared__ alignas(16) unsigned short Ps[8][16 * 64];
  const int tid = threadIdx.x;
  const int l = tid & 63, w = tid >> 6;
  const int lr = l & 15, lg = l >> 4;
  const int id = blockIdx.x;
  const int half = id >> 8, rr = id & 255;
  const int bx = rr & 15;
  const int bh = (rr >> 4) | (half << 4);
  const int qtb = half ? (15 - bx) : bx;
  const int b = bh >> 4, h = bh & 15;
  const unsigned short* Qb = qkv + (size_t)b * T * E + h * 64;
  const unsigned short* Kb = Qb + 1024;
  const unsigned short* Vb = Qb + 2048;
  const int kr = tid >> 3;          // staging row 0..63
  const int js = tid & 7;           // staging 16B slot 0..7
  unsigned short* PsW = Ps[w];

  const int qrow = qtb * 128 + w * 16;
  const int nt = 2 * qtb + 2;

  // per-thread staging sources (pre-swizzled K source; linear V source)
  const unsigned short* sK = Kb + (size_t)kr * E + ((js ^ (kr & 7)) << 3);
  const unsigned short* sV = Vb + (size_t)kr * E + (js << 3);
  const size_t tileStep = (size_t)64 * E;

  bf16x8 aq[2];
#pragma unroll
  for (int dc = 0; dc < 2; ++dc)
    aq[dc] = *reinterpret_cast<const bf16x8*>(Qb + (size_t)(qrow + lr) * E + dc * 32 + lg * 8);

  float mr[4], ls[4];
  f32x4 accO[4] = {};
#pragma unroll
  for (int r = 0; r < 4; ++r) { mr[r] = -1e30f; ls[r] = 0.f; }

  // ---- prologue: tile 0 into buffer 0; V(1) into regs ----
  __builtin_amdgcn_global_load_lds((gvoid*)sK, (svoid*)(&Ks[0][w * 512]), 16, 0, 0);
  ushort8 vreg = *reinterpret_cast<const ushort8*>(sV);
#pragma unroll
  for (int e = 0; e < 8; ++e) {
    int d = js * 8 + e;
    int swz = (d ^ (d >> 3)) & 7;
    Vt[0][d * 64 + ((((kr >> 3) ^ swz) << 3) | (kr & 7))] = (unsigned short)vreg[e];
  }
  if (nt > 1) vreg = *reinterpret_cast<const ushort8*>(sV + tileStep);
  __syncthreads();

  for (int t = 0; t < nt; ++t) {
    const int cur = t & 1;
    // stage tile t+1 into back buffer (overlapped with this tile's compute)
    if (t + 1 < nt) {
      __builtin_amdgcn_global_load_lds((gvoid*)(sK + (size_t)(t + 1) * tileStep),
                                       (svoid*)(&Ks[cur ^ 1][w * 512]), 16, 0, 0);
      unsigned short* VtB = Vt[cur ^ 1];
#pragma unroll
      for (int e = 0; e < 8; ++e) {
        int d = js * 8 + e;
        int swz = (d ^ (d >> 3)) & 7;
        VtB[d * 64 + ((((kr >> 3) ^ swz) << 3) | (kr & 7))] = (unsigned short)vreg[e];
      }
    }
    if (t + 2 < nt)
      vreg = *reinterpret_cast<const ushort8*>(sV + (size_t)(t + 2) * tileStep);

    // S = Q K^T
    const unsigned short* KsC = Ks[cur];
    f32x4 s[4] = {};
    __builtin_amdgcn_s_setprio(1);
#pragma unroll
    for (int n = 0; n < 4; ++n)
#pragma unroll
      for (int dc = 0; dc < 2; ++dc) {
        bf16x8 bk = *reinterpret_cast<const bf16x8*>(
            KsC + (n * 16 + lr) * 64 + (((dc * 4 + lg) ^ (lr & 7)) << 3));
        s[n] = __builtin_amdgcn_mfma_f32_16x16x32_bf16(aq[dc], bk, s[n], 0, 0, 0);
      }
    __builtin_amdgcn_s_setprio(0);

    // scale + causal mask
    const bool needMask = (t * 64 + 63) > qrow;   // wave-uniform
#pragma unroll
    for (int n = 0; n < 4; ++n) {
      const int gcol = t * 64 + n * 16 + lr;
#pragma unroll
      for (int r = 0; r < 4; ++r) {
        float v = s[n][r] * 0.125f;
        if (needMask && gcol > qrow + lg * 4 + r) v = -1e30f;
        s[n][r] = v;
      }
    }
    // online softmax with defer-max
    float pm[4];
#pragma unroll
    for (int r = 0; r < 4; ++r) {
      pm[r] = fmaxf(fmaxf(s[0][r], s[1][r]), fmaxf(s[2][r], s[3][r]));
#pragma unroll
      for (int off = 1; off < 16; off <<= 1)
        pm[r] = fmaxf(pm[r], __shfl_xor(pm[r], off));
    }
    bool need = (pm[0] > mr[0] + 8.f) | (pm[1] > mr[1] + 8.f) |
                (pm[2] > mr[2] + 8.f) | (pm[3] > mr[3] + 8.f);
    if (__any(need)) {
#pragma unroll
      for (int r = 0; r < 4; ++r) {
        float mn = fmaxf(mr[r], pm[r]);
        float al = __expf(mr[r] - mn);
        mr[r] = mn;
        ls[r] *= al;
#pragma unroll
        for (int dn = 0; dn < 4; ++dn) accO[dn][r] *= al;
      }
    }
    // P = exp(S-m) -> per-wave LDS (swizzled)
#pragma unroll
    for (int n = 0; n < 4; ++n)
#pragma unroll
      for (int r = 0; r < 4; ++r) {
        float p = __expf(s[n][r] - mr[r]);
        ls[r] += p;
        int row = lg * 4 + r, col = n * 16 + lr;
        PsW[row * 64 + ((((col >> 3) ^ (row & 7)) << 3) | (col & 7))] = f2bf(p);
      }
    asm volatile("s_waitcnt lgkmcnt(0)" ::: "memory");  // own-wave P (+Vt) writes done
    __builtin_amdgcn_sched_barrier(0);

    // O += P V
    const unsigned short* VtC = Vt[cur];
    __builtin_amdgcn_s_setprio(1);
#pragma unroll
    for (int kk = 0; kk < 2; ++kk) {
      bf16x8 ap = *reinterpret_cast<const bf16x8*>(
          PsW + lr * 64 + (((kk * 4 + lg) ^ (lr & 7)) << 3));
#pragma unroll
      for (int dn = 0; dn < 4; ++dn) {
        int d = dn * 16 + lr;
        int swz = (d ^ (d >> 3)) & 7;
        bf16x8 bv = *reinterpret_cast<const bf16x8*>(
            VtC + d * 64 + (((kk * 4 + lg) ^ swz) << 3));
        accO[dn] = __builtin_amdgcn_mfma_f32_16x16x32_bf16(ap, bv, accO[dn], 0, 0, 0);
      }
    }
    __builtin_amdgcn_s_setprio(0);

    __syncthreads();  // drains K-DMA(t+1) + V(t+2) loads (in flight all tile);
                      // all waves done reading buf[cur] before it is re-staged
  } // t

#pragma unroll
  for (int r = 0; r < 4; ++r) {
#pragma unroll
    for (int off = 1; off < 16; off <<= 1)
      ls[r] += __shfl_xor(ls[r], off);
    ls[r] = 1.f / ls[r];
  }
#pragma unroll
  for (int dn = 0; dn < 4; ++dn)
#pragma unroll
    for (int r = 0; r < 4; ++r) {
      int row = qrow + lg * 4 + r;
      int col = h * 64 + dn * 16 + lr;
      o[(size_t)(b * T + row) * 1024 + col] = f2bf(accO[dn][r] * ls[r]);
    }
}

extern "C" void kernel_launch(void* const* d_in, const int* in_sizes, int n_in,
                              void* d_out, int out_size, void* d_ws, size_t ws_size,
                              hipStream_t stream) {
  const float* x     = (const float*)d_in[0];   // [2,2048,1024]
  const float* w_qkv = (const float*)d_in[1];   // [3072,1024]
  const float* w_out = (const float*)d_in[2];   // [1024,1024]
  float* out = (float*)d_out;                   // [2,2048,1024] fp32

  unsigned short* xb    = (unsigned short*)d_ws;                  // 4096*1024
  unsigned short* wqkvb = xb    + (size_t)4096 * 1024;            // 3072*1024
  unsigned short* woutb = wqkvb + (size_t)3072 * 1024;            // 1024*1024
  unsigned short* qkv   = woutb + (size_t)1024 * 1024;            // 4096*3072
  unsigned short* attn  = qkv   + (size_t)4096 * 3072;            // 4096*1024

  cast_kernel<<<dim3(4096), 256, 0, stream>>>(x,     xb,    4096 * 1024 / 4);
  cast_kernel<<<dim3(3072), 256, 0, stream>>>(w_qkv, wqkvb, 3072 * 1024 / 4);
  cast_kernel<<<dim3(1024), 256, 0, stream>>>(w_out, woutb, 1024 * 1024 / 4);

  gemm_bt<true ><<<dim3(32, 24), 256, 0, stream>>>(xb,   wqkvb, (void*)qkv,  4096, 3072, 1024);
  attn_kernel  <<<dim3(512), 512, 0, stream>>>(qkv, attn);
  gemm_bt<false><<<dim3(32,  8), 256, 0, stream>>>(attn, woutb, (void*)out, 4096, 1024, 1024);
}

// Round 6
// 127.342 us; speedup vs baseline: 1.1300x; 1.1300x over previous
//
#include <hip/hip_runtime.h>
#include <hip/hip_bf16.h>

typedef __attribute__((ext_vector_type(8))) short bf16x8;
typedef __attribute__((ext_vector_type(8))) unsigned short ushort8;
typedef __attribute__((ext_vector_type(4))) float f32x4;
typedef __attribute__((ext_vector_type(16))) float f32x16;

typedef const __attribute__((address_space(1))) void gvoid;
typedef __attribute__((address_space(3))) void svoid;

__device__ __forceinline__ unsigned short f2bf(float f) {
  union { float f; unsigned int u; } v; v.f = f;
  unsigned int u = v.u;
  unsigned int r = (u + 0x7fffu + ((u >> 16) & 1u)) >> 16;
  return (unsigned short)r;
}

// ---------------- fp32 -> bf16 cast (vectorized) ----------------
__global__ void cast_kernel(const float* __restrict__ in, unsigned short* __restrict__ out, int n4) {
  int i = blockIdx.x * 256 + threadIdx.x;
  if (i < n4) {
    const float4 v = reinterpret_cast<const float4*>(in)[i];
    ushort4 o;
    o.x = f2bf(v.x); o.y = f2bf(v.y); o.z = f2bf(v.z); o.w = f2bf(v.w);
    reinterpret_cast<ushort4*>(out)[i] = o;
  }
}

// ---------------- C[M][N] = A[M][K] * B[N][K]^T, bf16 in, fp32 acc ----------------
// cols < qcols get scaled by qscale in the epilogue (folds attn's 1/8 into q).
template<bool OUT_BF16>
__global__ __launch_bounds__(256) void gemm_bt(const unsigned short* __restrict__ A,
                                               const unsigned short* __restrict__ B,
                                               void* __restrict__ Cv,
                                               int M, int N, int K,
                                               float qscale, int qcols) {
  constexpr int BM = 128, BK = 32;
  __shared__ alignas(16) unsigned short As[BM * BK];
  __shared__ alignas(16) unsigned short Bs[BM * BK];
  const int tid = threadIdx.x;
  const int l  = tid & 63;
  const int w  = tid >> 6;
  const int wr = w >> 1, wc = w & 1;
  const int lr = l & 15, lg = l >> 4;
  const long tile_m = (long)blockIdx.x * BM;
  const long tile_n = (long)blockIdx.y * BM;

  const int c0 = tid, c1 = tid + 256;
  const unsigned short* pa0 = A + (tile_m + (c0 >> 2)) * (long)K + (c0 & 3) * 8;
  const unsigned short* pa1 = A + (tile_m + (c1 >> 2)) * (long)K + (c1 & 3) * 8;
  const unsigned short* pb0 = B + (tile_n + (c0 >> 2)) * (long)K + (c0 & 3) * 8;
  const unsigned short* pb1 = B + (tile_n + (c1 >> 2)) * (long)K + (c1 & 3) * 8;
  unsigned short* lA0 = As + (w * 64) * 8;
  unsigned short* lA1 = As + (256 + w * 64) * 8;
  unsigned short* lB0 = Bs + (w * 64) * 8;
  unsigned short* lB1 = Bs + (256 + w * 64) * 8;

  f32x4 acc[4][4] = {};

  for (int k0 = 0; k0 < K; k0 += BK) {
    __syncthreads();
    __builtin_amdgcn_global_load_lds((gvoid*)(pa0 + k0), (svoid*)lA0, 16, 0, 0);
    __builtin_amdgcn_global_load_lds((gvoid*)(pa1 + k0), (svoid*)lA1, 16, 0, 0);
    __builtin_amdgcn_global_load_lds((gvoid*)(pb0 + k0), (svoid*)lB0, 16, 0, 0);
    __builtin_amdgcn_global_load_lds((gvoid*)(pb1 + k0), (svoid*)lB1, 16, 0, 0);
    __syncthreads();
    bf16x8 af[4], bfr[4];
#pragma unroll
    for (int m = 0; m < 4; ++m)
      af[m] = *reinterpret_cast<const bf16x8*>(As + (wr * 64 + m * 16 + lr) * BK + lg * 8);
#pragma unroll
    for (int n = 0; n < 4; ++n)
      bfr[n] = *reinterpret_cast<const bf16x8*>(Bs + (wc * 64 + n * 16 + lr) * BK + lg * 8);
#pragma unroll
    for (int m = 0; m < 4; ++m)
#pragma unroll
      for (int n = 0; n < 4; ++n)
        acc[m][n] = __builtin_amdgcn_mfma_f32_16x16x32_bf16(af[m], bfr[n], acc[m][n], 0, 0, 0);
  }

#pragma unroll
  for (int m = 0; m < 4; ++m)
#pragma unroll
    for (int n = 0; n < 4; ++n)
#pragma unroll
      for (int r = 0; r < 4; ++r) {
        long row = tile_m + wr * 64 + m * 16 + lg * 4 + r;
        long col = tile_n + wc * 64 + n * 16 + lr;
        float sc = (col < qcols) ? qscale : 1.0f;
        if (OUT_BF16)
          reinterpret_cast<unsigned short*>(Cv)[row * N + col] = f2bf(acc[m][n][r] * sc);
        else
          reinterpret_cast<float*>(Cv)[row * N + col] = acc[m][n][r] * sc;
      }
}

// ---------------- causal flash attention (swapped QK^T, in-register softmax) ---
// grid = 512 blocks x 256 threads (4 waves). Block i: half=i>>8, bx=i&15,
// bh=(i>>4)&15 | half<<4, qtb = half?15-bx:bx (complementary causal pairing).
// Wave w owns 32 q-rows [qtb*128 + w*32, +32). Per KV tile (64 k):
//   S^T = mfma_32x32x16(A=K, B=Q): lane holds 32 S-values, ALL for q-row
//   (lane&31); k = n*32 + (r&3)+8*(r>>2)+4*(lane>>5). Row-softmax is in-lane
//   + ONE shfl_xor(32). P->A-frags via v_cvt_pk_bf16_f32 + v_permlane32_swap.
//   O-rescale redistributed via 128B/wave LDS broadcast only on defer-max
//   trigger (THR=8). Q pre-scaled by 0.125 in GEMM1 epilogue.
// FIX vs round 5: needMask compares tile max-k against qrow0 (the wave's MIN
// q-row), not qrow0+31 — mask is needed iff max_k > min_q.
__global__ __launch_bounds__(256, 2) void attn_kernel(const unsigned short* __restrict__ qkv,
                                                      unsigned short* __restrict__ o) {
  constexpr int E = 3072, T = 2048;
  __shared__ alignas(16) unsigned short Ks[64 * 64];   // [k][d], slot ^= k&7
  __shared__ alignas(16) unsigned short Vt[64 * 64];   // [d][k], slot ^= (d^(d>>3))&7
  __shared__ float alBuf[4][32];
  const int tid = threadIdx.x;
  const int l = tid & 63, w = tid >> 6;
  const int hh = l >> 5;       // lane half
  const int lc = l & 31;       // lane col: q-row (softmax) / d-col (O)
  const int id = blockIdx.x;
  const int half = id >> 8, rr2 = id & 255;
  const int bx = rr2 & 15;
  const int bh = (rr2 >> 4) | (half << 4);
  const int qtb = half ? (15 - bx) : bx;
  const int b = bh >> 4, hd = bh & 15;
  const unsigned short* Qb = qkv + (size_t)b * T * E + hd * 64;
  const unsigned short* Kb = Qb + 1024;
  const unsigned short* Vb = Qb + 2048;

  const int qrow0 = qtb * 128 + w * 32;
  const int qg = qrow0 + lc;       // lane's q-row (global)
  const int nt = 2 * qtb + 2;

  // staging duty: 256 threads, 2 chunks each (rows 0..31 and 32..63)
  const int kr0 = tid >> 3, js0 = tid & 7;
  const int kr1 = kr0 + 32;
  const unsigned short* sK = Kb + (size_t)kr0 * E + js0 * 8;
  const unsigned short* sV = Vb + (size_t)kr0 * E + js0 * 8;
  const size_t tileStep = (size_t)64 * E;

  // Q fragments (B-operand): B[d][q]: col=lc=q, k(d) = 16c + 8*hh + j
  bf16x8 aq[4];
#pragma unroll
  for (int c = 0; c < 4; ++c)
    aq[c] = *reinterpret_cast<const bf16x8*>(Qb + (size_t)qg * E + c * 16 + hh * 8);

  f32x16 accO0 = {}, accO1 = {};   // O[q][d]: frag0 d=lc, frag1 d=32+lc
  float mL = -1e30f, ls = 0.f;

  // prologue: tile 0 into regs
  ushort8 k0 = *reinterpret_cast<const ushort8*>(sK);
  ushort8 k1 = *reinterpret_cast<const ushort8*>(sK + 32 * E);
  ushort8 v0 = *reinterpret_cast<const ushort8*>(sV);
  ushort8 v1 = *reinterpret_cast<const ushort8*>(sV + 32 * E);

  for (int t = 0; t < nt; ++t) {
    __syncthreads();   // all waves done reading previous tile
    *reinterpret_cast<ushort8*>(Ks + kr0 * 64 + ((js0 ^ (kr0 & 7)) << 3)) = k0;
    *reinterpret_cast<ushort8*>(Ks + kr1 * 64 + ((js0 ^ (kr1 & 7)) << 3)) = k1;
#pragma unroll
    for (int e = 0; e < 8; ++e) {
      int d = js0 * 8 + e;
      int swz = (d ^ (d >> 3)) & 7;
      Vt[d * 64 + ((((kr0 >> 3) ^ swz) << 3) | (kr0 & 7))] = (unsigned short)v0[e];
      Vt[d * 64 + ((((kr1 >> 3) ^ swz) << 3) | (kr1 & 7))] = (unsigned short)v1[e];
    }
    __syncthreads();   // staging visible
    if (t + 1 < nt) {  // prefetch next tile into regs (lands during compute)
      const unsigned short* nK = sK + (size_t)(t + 1) * tileStep;
      const unsigned short* nV = sV + (size_t)(t + 1) * tileStep;
      k0 = *reinterpret_cast<const ushort8*>(nK);
      k1 = *reinterpret_cast<const ushort8*>(nK + 32 * E);
      v0 = *reinterpret_cast<const ushort8*>(nV);
      v1 = *reinterpret_cast<const ushort8*>(nV + 32 * E);
    }

    if (t * 64 > qrow0 + 31) continue;   // wave-uniform: tile fully masked

    // ---- S^T = K · Q^T : D[k][q], 2 frags (k 0..31, 32..63) ----
    f32x16 sT0 = {}, sT1 = {};
#pragma unroll
    for (int c = 0; c < 4; ++c) {
      int sl = ((2 * c + hh) ^ (lc & 7)) << 3;
      bf16x8 ak0 = *reinterpret_cast<const bf16x8*>(Ks + lc * 64 + sl);
      bf16x8 ak1 = *reinterpret_cast<const bf16x8*>(Ks + (32 + lc) * 64 + sl);
      sT0 = __builtin_amdgcn_mfma_f32_32x32x16_bf16(ak0, aq[c], sT0, 0, 0, 0);
      sT1 = __builtin_amdgcn_mfma_f32_32x32x16_bf16(ak1, aq[c], sT1, 0, 0, 0);
    }

    // ---- causal mask + row max (all in-lane; k = t*64+32n+(r&3)+8*(r>>2)+4hh) --
    const bool needMask = (t * 64 + 63) > qrow0;   // FIX: max_k vs MIN q of wave
    float pm = -1e30f;
#pragma unroll
    for (int r = 0; r < 16; ++r) {
      int kb = t * 64 + (r & 3) + 8 * (r >> 2) + 4 * hh;
      float a0 = sT0[r], a1 = sT1[r];
      if (needMask) {
        if (kb > qg) a0 = -1e30f;
        if (kb + 32 > qg) a1 = -1e30f;
      }
      sT0[r] = a0; sT1[r] = a1;
      pm = fmaxf(pm, fmaxf(a0, a1));
    }
    pm = fmaxf(pm, __shfl_xor(pm, 32));   // lane pair shares the q-row

    // ---- defer-max (THR=8): rescale O only when max grows materially ----
    if (__any(pm > mL + 8.f)) {
      float mn = fmaxf(mL, pm);
      float al = __expf(mL - mn);
      mL = mn;
      ls *= al;
      alBuf[w][lc] = al;
      asm volatile("s_waitcnt lgkmcnt(0)" ::: "memory");
      __builtin_amdgcn_sched_barrier(0);
#pragma unroll
      for (int r = 0; r < 16; ++r) {
        float alr = alBuf[w][(r & 3) + 8 * (r >> 2) + 4 * hh];
        accO0[r] *= alr;
        accO1[r] *= alr;
      }
    }

    // ---- P = exp(S-m); build PV A-frags in-register (cvt_pk + permlane32_swap) --
    bf16x8 pa[4];
    union U4 { unsigned int u[4]; bf16x8 v; };
#pragma unroll
    for (int n = 0; n < 2; ++n) {
      float p[16];
#pragma unroll
      for (int r = 0; r < 16; ++r) {
        float pv = __expf((n ? sT1[r] : sT0[r]) - mL);
        p[r] = pv;
        ls += pv;
      }
#pragma unroll
      for (int g = 0; g < 2; ++g) {     // frag c' = 2n + g, from p[8g..8g+7]
        unsigned int x0, x1, y0, y1;
        asm("v_cvt_pk_bf16_f32 %0, %1, %2" : "=v"(x0) : "v"(p[8 * g + 0]), "v"(p[8 * g + 1]));
        asm("v_cvt_pk_bf16_f32 %0, %1, %2" : "=v"(x1) : "v"(p[8 * g + 2]), "v"(p[8 * g + 3]));
        asm("v_cvt_pk_bf16_f32 %0, %1, %2" : "=v"(y0) : "v"(p[8 * g + 4]), "v"(p[8 * g + 5]));
        asm("v_cvt_pk_bf16_f32 %0, %1, %2" : "=v"(y1) : "v"(p[8 * g + 6]), "v"(p[8 * g + 7]));
        // dst_hi <-> src_lo: after swap x* = both low halves, y* = both highs;
        // per lane-half this yields contiguous k-runs (derivation in r5 notes)
        asm("v_permlane32_swap_b32 %0, %1" : "+v"(x0), "+v"(y0));
        asm("v_permlane32_swap_b32 %0, %1" : "+v"(x1), "+v"(y1));
        U4 fu;
        fu.u[0] = x0; fu.u[1] = x1; fu.u[2] = y0; fu.u[3] = y1;
        pa[2 * n + g] = fu.v;
      }
    }

    // ---- O += P V : B[k][d] from Vt; frag m: d = 32m + lc ----
#pragma unroll
    for (int cp = 0; cp < 4; ++cp) {
      int d0 = lc, d1 = 32 + lc;
      int sl0 = ((2 * cp + hh) ^ ((d0 ^ (d0 >> 3)) & 7)) << 3;
      int sl1 = ((2 * cp + hh) ^ ((d1 ^ (d1 >> 3)) & 7)) << 3;
      bf16x8 bv0 = *reinterpret_cast<const bf16x8*>(Vt + d0 * 64 + sl0);
      bf16x8 bv1 = *reinterpret_cast<const bf16x8*>(Vt + d1 * 64 + sl1);
      accO0 = __builtin_amdgcn_mfma_f32_32x32x16_bf16(pa[cp], bv0, accO0, 0, 0, 0);
      accO1 = __builtin_amdgcn_mfma_f32_32x32x16_bf16(pa[cp], bv1, accO1, 0, 0, 0);
    }
  } // t

  // ---- finalize: total row-sum, redistribute 1/ls to C/D rows, store ----
  float inv = 1.f / (ls + __shfl_xor(ls, 32));
  alBuf[w][lc] = inv;
  asm volatile("s_waitcnt lgkmcnt(0)" ::: "memory");
  __builtin_amdgcn_sched_barrier(0);
#pragma unroll
  for (int r = 0; r < 16; ++r) {
    int q = (r & 3) + 8 * (r >> 2) + 4 * hh;
    float iv = alBuf[w][q];
    size_t row = (size_t)(b * T + qrow0 + q) * 1024 + hd * 64;
    o[row + lc]      = f2bf(accO0[r] * iv);
    o[row + 32 + lc] = f2bf(accO1[r] * iv);
  }
}

extern "C" void kernel_launch(void* const* d_in, const int* in_sizes, int n_in,
                              void* d_out, int out_size, void* d_ws, size_t ws_size,
                              hipStream_t stream) {
  const float* x     = (const float*)d_in[0];   // [2,2048,1024]
  const float* w_qkv = (const float*)d_in[1];   // [3072,1024]
  const float* w_out = (const float*)d_in[2];   // [1024,1024]
  float* out = (float*)d_out;                   // [2,2048,1024] fp32

  unsigned short* xb    = (unsigned short*)d_ws;                  // 4096*1024
  unsigned short* wqkvb = xb    + (size_t)4096 * 1024;            // 3072*1024
  unsigned short* woutb = wqkvb + (size_t)3072 * 1024;            // 1024*1024
  unsigned short* qkv   = woutb + (size_t)1024 * 1024;            // 4096*3072
  unsigned short* attn  = qkv   + (size_t)4096 * 3072;            // 4096*1024

  cast_kernel<<<dim3(4096), 256, 0, stream>>>(x,     xb,    4096 * 1024 / 4);
  cast_kernel<<<dim3(3072), 256, 0, stream>>>(w_qkv, wqkvb, 3072 * 1024 / 4);
  cast_kernel<<<dim3(1024), 256, 0, stream>>>(w_out, woutb, 1024 * 1024 / 4);

  gemm_bt<true ><<<dim3(32, 24), 256, 0, stream>>>(xb,   wqkvb, (void*)qkv,  4096, 3072, 1024,
                                                   0.125f, 1024);
  attn_kernel  <<<dim3(512), 256, 0, stream>>>(qkv, attn);
  gemm_bt<false><<<dim3(32,  8), 256, 0, stream>>>(attn, woutb, (void*)out, 4096, 1024, 1024,
                                                   1.0f, 0);
}